// Round 1
// baseline (484.398 us; speedup 1.0000x reference)
//
#include <hip/hip_runtime.h>

// GCNConv: out = segment_sum(edge_vals * x[edge_col], edge_row) @ W
// N=100000 nodes, E=1600000 edges, D_IN=D_OUT=64, all fp32 (indices int32).
//
// Baseline structure (round 0):
//   1) zero agg workspace (N*64 fp32 = 25.6 MB) in d_ws via hipMemsetAsync
//   2) scatter: thread = (edge, feature). 64 lanes/edge -> coalesced 256B
//      gather of x[col,:], coalesced atomicAdd into agg[row,:]
//   3) GEMM: out[n,:] = agg[n,:] @ W, W staged in LDS (16 KB), 4 rows/block

#define N_NODES 100000
#define N_EDGES 1600000
#define DF 64

__global__ __launch_bounds__(256) void gcn_scatter(
    const float* __restrict__ x,
    const float* __restrict__ edge_vals,
    const int* __restrict__ edge_row,
    const int* __restrict__ edge_col,
    float* __restrict__ agg)
{
    int t = blockIdx.x * 256 + threadIdx.x;
    int e = t >> 6;        // edge index
    int f = t & 63;        // feature index
    if (e >= N_EDGES) return;
    int r = edge_row[e];
    int c = edge_col[e];
    float v = edge_vals[e];
    atomicAdd(&agg[r * DF + f], v * x[c * DF + f]);
}

__global__ __launch_bounds__(256) void gcn_gemm(
    const float* __restrict__ agg,
    const float* __restrict__ w,
    float* __restrict__ out)
{
    __shared__ float ws[DF * DF];   // W, row-major [k][j]
    __shared__ float as[4 * DF];    // 4 agg rows

    // load W (64x64 fp32 = 16 KB)
    for (int i = threadIdx.x; i < DF * DF; i += 256) ws[i] = w[i];

    int rowBase = blockIdx.x * 4;
    int r = threadIdx.x >> 6;      // 0..3
    int j = threadIdx.x & 63;      // output feature
    int row = rowBase + r;

    // stage 4 agg rows (each thread loads one element)
    as[r * DF + j] = (row < N_NODES) ? agg[row * DF + j] : 0.0f;
    __syncthreads();

    if (row >= N_NODES) return;

    float acc = 0.0f;
    #pragma unroll
    for (int k = 0; k < DF; ++k) {
        acc += as[r * DF + k] * ws[k * DF + j];
    }
    out[row * DF + j] = acc;
}

extern "C" void kernel_launch(void* const* d_in, const int* in_sizes, int n_in,
                              void* d_out, int out_size, void* d_ws, size_t ws_size,
                              hipStream_t stream)
{
    const float* x    = (const float*)d_in[0];   // [N, 64]
    const float* w    = (const float*)d_in[1];   // [64, 64]
    const float* ev   = (const float*)d_in[2];   // [E]
    const int*   erow = (const int*)d_in[3];     // [E]
    const int*   ecol = (const int*)d_in[4];     // [E]
    float* out = (float*)d_out;                  // [N, 64]
    float* agg = (float*)d_ws;                   // [N, 64] scratch

    // zero the accumulator (d_ws is re-poisoned to 0xAA before every launch)
    hipMemsetAsync(agg, 0, (size_t)N_NODES * DF * sizeof(float), stream);

    // scatter-add: E*64 threads
    {
        long long total = (long long)N_EDGES * DF;
        int blocks = (int)((total + 255) / 256);
        gcn_scatter<<<blocks, 256, 0, stream>>>(x, ev, erow, ecol, agg);
    }

    // dense GEMM: out = agg @ W
    {
        int blocks = (N_NODES + 3) / 4;   // 25000
        gcn_gemm<<<blocks, 256, 0, stream>>>(agg, w, out);
    }
}

// Round 2
// 375.940 us; speedup vs baseline: 1.2885x; 1.2885x over previous
//
#include <hip/hip_runtime.h>

// GCNConv: out = segment_sum(edge_vals * x[edge_col], edge_row) @ W
// N=100000, E=1600000, D=64, fp32.
//
// Round 2: kill the fp32 atomics (R1: 400 MB WRITE_SIZE = 102.4M atomic dwords
// written through L2). Build CSR on-device (histogram -> scan -> fill), then
// atomic-free wave-per-node gather aggregation fused with the W GEMM.

#define N_NODES 100000
#define N_EDGES 1600000
#define DF 64
#define NB_SCAN 391   // ceil(100000/256); 391*256 = 100096

// ws layout (byte offsets); total ~13.9 MB (R1 proved ws >= 25.6 MB)
#define OFF_COUNTS 0u         // 100000 ints: counts -> exclusive offsets -> (post-fill) bucket ends
#define OFF_EOFF   401408u    // 100000 ints: block-local exclusive scan
#define OFF_BSUMS  802816u    // 512 ints: per-block totals
#define OFF_CSR    1048576u   // 1.6M int2 {col, val-bits} = 12.8 MB

__global__ __launch_bounds__(256) void gcn_hist(
    const int* __restrict__ erow, int* __restrict__ counts)
{
    int e = blockIdx.x * 256 + threadIdx.x;
    if (e < N_EDGES) atomicAdd(&counts[erow[e]], 1);
}

// block-local exclusive scan of counts; also emit per-block totals
__global__ __launch_bounds__(256) void gcn_scan1(
    const int* __restrict__ counts, int* __restrict__ eoff, int* __restrict__ bsums)
{
    __shared__ int tmp[256];
    int i = blockIdx.x * 256 + threadIdx.x;
    int v = (i < N_NODES) ? counts[i] : 0;
    tmp[threadIdx.x] = v;
    __syncthreads();
    int val = v;
    for (int off = 1; off < 256; off <<= 1) {
        int t = (threadIdx.x >= off) ? tmp[threadIdx.x - off] : 0;
        __syncthreads();
        val += t;
        tmp[threadIdx.x] = val;
        __syncthreads();
    }
    if (i < N_NODES) eoff[i] = val - v;                 // exclusive within block
    if (threadIdx.x == 255) bsums[blockIdx.x] = val;    // block total
}

// exclusive scan of the 391 block totals, in place (single block)
__global__ __launch_bounds__(512) void gcn_scan2(int* __restrict__ bsums)
{
    __shared__ int tmp[512];
    int i = threadIdx.x;
    int v = (i < NB_SCAN) ? bsums[i] : 0;
    tmp[i] = v;
    __syncthreads();
    int val = v;
    for (int off = 1; off < 512; off <<= 1) {
        int t = (i >= off) ? tmp[i - off] : 0;
        __syncthreads();
        val += t;
        tmp[i] = val;
        __syncthreads();
    }
    if (i < NB_SCAN) bsums[i] = val - v;                // exclusive
}

// global exclusive offsets = block-local + block base; write into counts array
__global__ __launch_bounds__(256) void gcn_scan3(
    const int* __restrict__ eoff, const int* __restrict__ bsums, int* __restrict__ offs)
{
    int i = blockIdx.x * 256 + threadIdx.x;
    if (i < N_NODES) offs[i] = eoff[i] + bsums[blockIdx.x];
}

// slot-assign: consumes offs via atomicAdd; afterwards offs[n] == end(n)
__global__ __launch_bounds__(256) void gcn_fill(
    const int* __restrict__ erow, const int* __restrict__ ecol,
    const float* __restrict__ ev, int* __restrict__ offs, int2* __restrict__ csr)
{
    int e = blockIdx.x * 256 + threadIdx.x;
    if (e < N_EDGES) {
        int r = erow[e];
        int pos = atomicAdd(&offs[r], 1);
        csr[pos] = make_int2(ecol[e], __float_as_int(ev[e]));
    }
}

// wave-per-node aggregation (atomic-free) fused with out = agg @ W
// grid: 25000 blocks x 256 (4 waves/block); 25000*4 == N_NODES exactly
__global__ __launch_bounds__(256) void gcn_agg_gemm(
    const float* __restrict__ x, const float* __restrict__ w,
    const int* __restrict__ ends, const int2* __restrict__ csr,
    float* __restrict__ out)
{
    __shared__ float ws_[DF * DF];   // 16 KB: W row-major [k][j]
    __shared__ float as_[4 * DF];    // 4 agg rows
    for (int i = threadIdx.x; i < DF * DF; i += 256) ws_[i] = w[i];

    int wv   = threadIdx.x >> 6;     // wave in block: 0..3
    int lane = threadIdx.x & 63;     // feature index
    int node = blockIdx.x * 4 + wv;

    int end   = ends[node];
    int start = (node == 0) ? 0 : ends[node - 1];

    float acc = 0.0f;
    int i = start;
    // 4-wide unroll: 4 independent gathers in flight per wave
    for (; i + 4 <= end; i += 4) {
        int2 e0 = csr[i];
        int2 e1 = csr[i + 1];
        int2 e2 = csr[i + 2];
        int2 e3 = csr[i + 3];
        float g0 = x[e0.x * DF + lane];
        float g1 = x[e1.x * DF + lane];
        float g2 = x[e2.x * DF + lane];
        float g3 = x[e3.x * DF + lane];
        acc += __int_as_float(e0.y) * g0;
        acc += __int_as_float(e1.y) * g1;
        acc += __int_as_float(e2.y) * g2;
        acc += __int_as_float(e3.y) * g3;
    }
    for (; i < end; ++i) {
        int2 e = csr[i];
        acc += __int_as_float(e.y) * x[e.x * DF + lane];
    }

    as_[wv * DF + lane] = acc;
    __syncthreads();

    float o = 0.0f;
    #pragma unroll
    for (int k = 0; k < DF; ++k) {
        o += as_[wv * DF + k] * ws_[k * DF + lane];   // as_: broadcast; ws_: 2-way (free)
    }
    out[node * DF + lane] = o;
}

extern "C" void kernel_launch(void* const* d_in, const int* in_sizes, int n_in,
                              void* d_out, int out_size, void* d_ws, size_t ws_size,
                              hipStream_t stream)
{
    const float* x    = (const float*)d_in[0];   // [N, 64]
    const float* w    = (const float*)d_in[1];   // [64, 64]
    const float* ev   = (const float*)d_in[2];   // [E]
    const int*   erow = (const int*)d_in[3];     // [E]
    const int*   ecol = (const int*)d_in[4];     // [E]
    float* out = (float*)d_out;

    char* ws = (char*)d_ws;
    int*  counts = (int*)(ws + OFF_COUNTS);      // counts -> offsets -> ends
    int*  eoff   = (int*)(ws + OFF_EOFF);
    int*  bsums  = (int*)(ws + OFF_BSUMS);
    int2* csr    = (int2*)(ws + OFF_CSR);

    const int EB = (N_EDGES + 255) / 256;        // 6250

    hipMemsetAsync(counts, 0, (size_t)N_NODES * sizeof(int), stream);
    gcn_hist <<<EB, 256, 0, stream>>>(erow, counts);
    gcn_scan1<<<NB_SCAN, 256, 0, stream>>>(counts, eoff, bsums);
    gcn_scan2<<<1, 512, 0, stream>>>(bsums);
    gcn_scan3<<<NB_SCAN, 256, 0, stream>>>(eoff, bsums, counts);
    gcn_fill <<<EB, 256, 0, stream>>>(erow, ecol, ev, counts, csr);
    gcn_agg_gemm<<<N_NODES / 4, 256, 0, stream>>>(x, w, counts, csr, out);
}